// Round 11
// baseline (700.938 us; speedup 1.0000x reference)
//
#include <hip/hip_runtime.h>
#include <hip/hip_bf16.h>

typedef unsigned short u16;
typedef unsigned int u32;
typedef __attribute__((ext_vector_type(4))) float f32x4;
typedef __attribute__((ext_vector_type(8))) short bf16x8;

struct __align__(8) ew_t { int s; float w; };   // packed edge record

#define WLOOP (2.0f/3.0f - 1.0f)      /* -1/3 */
#define WEDGE (-(2.0f/3.0f))          /* -(2/lambda_max) */

__device__ __forceinline__ float bf2f(u16 h){ u32 u = ((u32)h)<<16; float f; __builtin_memcpy(&f,&u,4); return f; }
__device__ __forceinline__ u16 f2bf(float f){ u32 u; __builtin_memcpy(&u,&f,4); u32 r = u + 0x7fffu + ((u>>16)&1u); return (u16)(r>>16); }

__device__ __forceinline__ void async16(u16* lds, const u16* g){
  __builtin_amdgcn_global_load_lds((const __attribute__((address_space(1))) u32*)g,
                                   (__attribute__((address_space(3))) u32*)lds, 16, 0, 0);
}

// ---------------- graph prep ----------------
__global__ void k_hist(const int* __restrict__ ei, int E, int* cntf, int* cntb){
  int e = blockIdx.x*256 + threadIdx.x; if (e>=E) return;
  atomicAdd(&cntf[ei[e]],1); atomicAdd(&cntb[ei[E+e]],1);
}
__global__ void k_dinv(const int* __restrict__ cntf, float* dinv, int N){
  int n = blockIdx.x*256+threadIdx.x; if(n>=N) return;
  int d = cntf[n]; dinv[n] = d>0 ? rsqrtf((float)d) : 0.f;
}
__global__ void k_scanA(const int* __restrict__ cnt, int* excl, int* bsum, int n){
  __shared__ int sh[256]; int i = blockIdx.x*256+threadIdx.x;
  int v = (i<n)? cnt[i]:0; sh[threadIdx.x]=v; __syncthreads();
  for (int off=1; off<256; off<<=1){
    int t = (threadIdx.x>=off)? sh[threadIdx.x-off]:0; __syncthreads();
    sh[threadIdx.x]+=t; __syncthreads();
  }
  if (i<n) excl[i]=sh[threadIdx.x]-v;
  if (threadIdx.x==255) bsum[blockIdx.x]=sh[255];
}
__global__ void k_scanB(int* bsum, int nb, int* total){
  __shared__ int sh[512]; int t = threadIdx.x;
  int v = (t<nb)? bsum[t]:0; sh[t]=v; __syncthreads();
  for(int off=1; off<512; off<<=1){
    int a = (t>=off)? sh[t-off]:0; __syncthreads();
    sh[t]+=a; __syncthreads();
  }
  if (t<nb) bsum[t]=sh[t]-v;
  if (t==511) *total = sh[511];
}
__global__ void k_scanC(int* excl, const int* __restrict__ bsum, int n, int* cur){
  int i = blockIdx.x*256+threadIdx.x; if(i>=n) return;
  int v = excl[i]+bsum[blockIdx.x]; excl[i]=v; cur[i]=v;
}
__global__ void k_fill(const int* __restrict__ ei, int E, const float* __restrict__ dinv,
                       int* curf, int* curb, ew_t* ewf, ew_t* ewb){
  int e = blockIdx.x*256+threadIdx.x; if(e>=E) return;
  int r = ei[e], c = ei[E+e];
  float w = WEDGE * dinv[r]*dinv[c];
  int pf = atomicAdd(&curf[r],1); ewf[pf] = {c, w};
  int pb = atomicAdd(&curb[c],1); ewb[pb] = {r, w};
}

// ---------------- layer 1 (scalar cheb), predicated 8-batch gathers ----------------
__global__ void k_sprop(const float* __restrict__ t1f, const float* __restrict__ t0f, float* df,
                        const float* __restrict__ t1b, const float* __restrict__ t0b, float* db,
                        const int* __restrict__ offf, const ew_t* __restrict__ ewfa,
                        const int* __restrict__ offb, const ew_t* __restrict__ ewba,
                        int N){
  int i = blockIdx.x*256+threadIdx.x;
  int dir = 0; if (i >= N){ i -= N; dir = 1; }
  if (i >= N) return;
  const float* t1; const float* t0; float* d; const int* off; const ew_t* ew;
  if (dir==0){ t1=t1f; t0=t0f; d=df; off=offf; ew=ewfa; }
  else       { t1=t1b; t0=t0b; d=db; off=offb; ew=ewba; }
  float a = WLOOP * t1[i];
  int e = off[i], e1 = off[i+1];
  for (; e < e1; e += 8){
    #pragma unroll
    for (int j=0;j<8;j++){
      int idx = e + j; bool v = idx < e1;
      ew_t p = ew[v ? idx : e1-1];
      a += (v ? p.w : 0.f) * t1[p.s];
    }
  }
  d[i] = t0 ? (2.f*a - t0[i]) : a;
}

__global__ void k_expand(const float* __restrict__ x,
   const float* __restrict__ cf1, const float* __restrict__ cf2, const float* __restrict__ cf3, const float* __restrict__ cf4,
   const float* __restrict__ cb1, const float* __restrict__ cb2, const float* __restrict__ cb3, const float* __restrict__ cb4,
   const float* __restrict__ W1f, const float* __restrict__ b1f,
   const float* __restrict__ W1b, const float* __restrict__ b1b,
   u16* __restrict__ T, int N){
  __shared__ float swf[640], swb[640], sbias[128];
  int tid = threadIdx.x;
  for (int i=tid;i<640;i+=256){ swf[i]=W1f[i]; swb[i]=W1b[i]; }
  if (tid<128) sbias[tid]=b1f[tid]+b1b[tid];
  __syncthreads();
  int j = tid & 127; int n = blockIdx.x*2 + (tid>>7);
  if (n>=N) return;
  float xx = x[n];
  float acc = sbias[j] + xx*(swf[j]+swb[j]);
  acc += cf1[n]*swf[128+j]; acc += cf2[n]*swf[256+j]; acc += cf3[n]*swf[384+j]; acc += cf4[n]*swf[512+j];
  acc += cb1[n]*swb[128+j]; acc += cb2[n]*swb[256+j]; acc += cb3[n]*swb[384+j]; acc += cb4[n]*swb[512+j];
  T[(size_t)n*1152 + j] = f2bf(fmaxf(acc,0.f));
}

// ---------------- layer 2 vector props (bf16 rows, fp32 accum), predicated 8-batch ----------------
__global__ void k_vprop(u16* __restrict__ T,
   const int* __restrict__ offf, const ew_t* __restrict__ ewfa,
   const int* __restrict__ offb, const ew_t* __restrict__ ewba,
   int ssf, int dsf, int psf, int ssb, int dsb, int psb, int N){
  int gid = blockIdx.x*256 + threadIdx.x;
  int wid = gid>>6, l = threadIdx.x & 63;
  int dir = 0; if (wid >= N){ wid -= N; dir = 1; }
  if (wid >= N) return;
  const int* off; const ew_t* ew; int ss,ds,ps;
  if (!dir){ off=offf;ew=ewfa;ss=ssf;ds=dsf;ps=psf; }
  else     { off=offb;ew=ewba;ss=ssb;ds=dsb;ps=psb; }
  const u16* Tss = T + (size_t)ss*128 + 2*l;                  // + row*1152
  u32 u = *(const u32*)(Tss + (size_t)wid*1152);
  float a0 = WLOOP*bf2f(u&0xffff), a1 = WLOOP*bf2f(u>>16);
  int e = off[wid], e1 = off[wid+1];
  for (; e < e1; e += 8){
    #pragma unroll
    for (int j=0;j<8;j++){
      int idx = e + j; bool v = idx < e1;
      ew_t p = ew[v ? idx : e1-1];
      float wj = v ? p.w : 0.f;
      u32 g = *(const u32*)(Tss + (size_t)p.s*1152);
      a0 += wj*bf2f(g&0xffff);
      a1 += wj*bf2f(g>>16);
    }
  }
  float r0=a0, r1=a1;
  if (ps >= 0){
    u32 up = *(const u32*)(T + ((size_t)wid*1152 + ps*128) + 2*l);
    r0 = 2.f*a0 - bf2f(up&0xffff); r1 = 2.f*a1 - bf2f(up>>16);
  }
  *(u32*)(T + ((size_t)wid*1152 + ds*128) + 2*l) = ((u32)f2bf(r1)<<16) | (u32)f2bf(r0);
}

// ---------------- weight prep: fragment-tiled Wt2 ----------------
__global__ void k_wprep(const float* __restrict__ W2f, const float* __restrict__ W2b,
                        const float* __restrict__ b2f, const float* __restrict__ b2b,
                        u16* __restrict__ Wt2, float* __restrict__ bias2){
  int i = blockIdx.x*256+threadIdx.x;
  if (i < 512) bias2[i] = b2f[i]+b2b[i];
  if (i >= 512*1152) return;
  int j = i&7, l = (i>>3)&63, nt = (i>>9)&31, t = i>>14;
  int col = nt*16 + (l&15);
  int k   = t*32 + (l>>4)*8 + j;
  int s2 = k>>7, c = k&127;
  float v;
  if (s2==0)      v = W2f[c*512+col] + W2b[c*512+col];
  else if (s2<5)  v = W2f[(s2*128+c)*512 + col];
  else            v = W2b[((s2-4)*128+c)*512 + col];
  Wt2[i] = f2bf(v);
}

// ---------------- pooled GEMM: T[M x 1152] @ W^T -> relu -> segment-sum ----------------
// R10 structure (BM=128, BN=256, 8 waves, acc[4][4], 2 blocks/CU, XCD-pairing swizzle)
// + A depth-2 prefetch: triple-buffered A-LDS, issue order [LOADB(t+1), STAGE(t+2)],
// steady vmcnt(6) keeps {stage(t+1), B(t+1), stage(t+2)} in flight and drains exactly
// stage(t)+B(t) (FIFO oldest-first, m135 semantics). 6-phase static unroll (rule #20).
__global__ __launch_bounds__(512, 4) void k_gemm(const u16* __restrict__ T, const u16* __restrict__ Wt2,
                        const float* __restrict__ bias2, const int* __restrict__ batch,
                        float* __restrict__ outp, int Mvalid, int NB){
  int bid = blockIdx.x;
  int r8 = bid & 7, q = bid >> 3;
  int bn = q & 1, bm = (q >> 1)*8 + r8;
  if (bm >= NB) return;
  __shared__ u16 Al[3][128*32];     // 8KB per buf, 24KB total
  int tid = threadIdx.x, w = tid>>6, l = tid&63;
  int wr = w>>2, wc = w&3;          // wave grid 2 x 4 -> per-wave 64 rows x 64 cols
  int hi = l>>4, lo = l&15;

  f32x4 acc[4][4];
  #pragma unroll
  for (int m=0;m<4;m++)
    #pragma unroll
    for (int n=0;n<4;n++){ acc[m][n][0]=0.f; acc[m][n][1]=0.f; acc[m][n][2]=0.f; acc[m][n][3]=0.f; }

  // A staging: thread -> (row = tid>>2, chunk slot = tid&3); source chunk pre-swizzled
  int sr = tid>>2, sp = tid&3;
  int csrc = ((sp ^ ((sr>>1)&3)))*8;
  const u16* asrc = T + (size_t)(bm*128 + sr)*1152 + csrc;
  const int adst = tid*8;                                  // linear dest
  // A fragment read base: same XOR on read side
  int rsw = (hi ^ ((lo>>1)&3))*8;
  const int abase = (wr*64 + lo)*32 + rsw;                 // + m*512
  // B fragment base: ntile = bn*16 + wc*4 + n; frag(t,ntile) at (t*32+ntile)*512 u16
  const u16* bsrc = Wt2 + ((size_t)(bn*16 + wc*4)*64 + l)*8;   // + t*16384 + n*512

  #define LOADB(dst, t_) do { \
    _Pragma("unroll") \
    for (int n_=0;n_<4;n_++) dst[n_] = *(const bf16x8*)(bsrc + (size_t)(t_)*16384 + n_*512); \
  } while(0)

  bf16x8 be[4], bo[4];
  // prologue: stage(0), B(0), stage(1)  (this FIFO order makes vmcnt(6) uniform)
  async16(&Al[0][adst], asrc);
  LOADB(be, 0);
  async16(&Al[1][adst], asrc + 32);

  #define GSTEP(tc, bufC, bufS, BC, BN_) do { \
    if ((tc)+1 < 36) LOADB(BN_, (tc)+1); \
    if ((tc)+2 < 36) async16(&Al[bufS][adst], asrc + ((tc)+2)*32); \
    if ((tc) < 34)      { asm volatile("s_waitcnt vmcnt(6)" ::: "memory"); } \
    else if ((tc)==34)  { asm volatile("s_waitcnt vmcnt(5)" ::: "memory"); } \
    else                { asm volatile("s_waitcnt vmcnt(0)" ::: "memory"); } \
    asm volatile("s_barrier" ::: "memory"); \
    __builtin_amdgcn_s_setprio(1); \
    _Pragma("unroll") \
    for (int m_=0;m_<4;m_++){ \
      bf16x8 af = *(const bf16x8*)&Al[bufC][abase + m_*512]; \
      _Pragma("unroll") \
      for (int n_=0;n_<4;n_++) \
        acc[m_][n_] = __builtin_amdgcn_mfma_f32_16x16x32_bf16(af, BC[n_], acc[m_][n_], 0, 0, 0); \
    } \
    __builtin_amdgcn_s_setprio(0); \
    asm volatile("s_barrier" ::: "memory"); \
  } while(0)

  for (int t0=0; t0<36; t0+=6){        // K = 1152 = 36*32; 6-phase: bufs mod 3, B-regs mod 2
    GSTEP(t0+0, 0, 2, be, bo);
    GSTEP(t0+1, 1, 0, bo, be);
    GSTEP(t0+2, 2, 1, be, bo);
    GSTEP(t0+3, 0, 2, bo, be);
    GSTEP(t0+4, 1, 0, be, bo);
    GSTEP(t0+5, 2, 1, bo, be);
  }
  #undef GSTEP
  #undef LOADB

  // epilogue: bias + relu + pooled segment-sum (batch sorted -> run-length over 16 rows)
  int bg[16];
  #pragma unroll
  for (int m=0;m<4;m++)
    #pragma unroll
    for (int j2=0;j2<4;j2++){
      int row = bm*128 + wr*64 + m*16 + hi*4 + j2;
      bg[m*4+j2] = (row < Mvalid) ? batch[row] : -1;
    }
  #pragma unroll
  for (int n=0;n<4;n++){
    int col = bn*256 + wc*64 + n*16 + lo;
    float bc = bias2[col];
    int cg2 = -1; float ssum = 0.f;
    #pragma unroll
    for (int idx=0; idx<16; idx++){
      int g = bg[idx];
      if (g >= 0){
        float val = fmaxf(acc[idx>>2][n][idx&3] + bc, 0.f);
        if (g != cg2){ if (cg2 >= 0) atomicAdd(&outp[(cg2<<9) + col], ssum); cg2 = g; ssum = 0.f; }
        ssum += val;
      }
    }
    if (cg2 >= 0) atomicAdd(&outp[(cg2<<9) + col], ssum);
  }
}

// per-block LDS histogram: ~200 global atomics total instead of 100k
__global__ void k_count(const int* __restrict__ batch, int* cg, int N){
  __shared__ int sh[64];
  int t = threadIdx.x;
  if (t < 64) sh[t] = 0;
  __syncthreads();
  int base = blockIdx.x*1024;
  #pragma unroll
  for (int i = base + t; i < base + 1024; i += 256){
    if (i < N) atomicAdd(&sh[batch[i]], 1);
  }
  __syncthreads();
  if (t < 64){ int v = sh[t]; if (v) atomicAdd(&cg[t], v); }
}

__global__ void k_div(float* out, const int* __restrict__ cg, int total){
  int i = blockIdx.x*256+threadIdx.x; if (i>=total) return;
  int g = i>>9; out[i] /= fmaxf((float)cg[g], 1.f);
}

extern "C" void kernel_launch(void* const* d_in, const int* in_sizes, int n_in,
                              void* d_out, int out_size, void* d_ws, size_t ws_size,
                              hipStream_t stream) {
  const float* x   = (const float*)d_in[0];
  const int*   ei  = (const int*)d_in[1];
  const int*   bat = (const int*)d_in[2];
  const float* W1f = (const float*)d_in[3];
  const float* b1f = (const float*)d_in[4];
  const float* W1b = (const float*)d_in[5];
  const float* b1b = (const float*)d_in[6];
  const float* W2f = (const float*)d_in[7];
  const float* b2f = (const float*)d_in[8];
  const float* W2b = (const float*)d_in[9];
  const float* b2b = (const float*)d_in[10];

  const int N  = in_sizes[0];
  const int E  = in_sizes[1] / 2;
  const int NP = ((N + 127)/128)*128;
  const int NB = NP/128;

  // ---- ws layout ----
  size_t p = 0;
  auto A = [&](size_t sz){ size_t r = p; p += (sz + 255) & ~(size_t)255; return r; };
  size_t o_cnt  = A(2*(size_t)N*4);          // cnt_f | cnt_b
  size_t o_offf = A(((size_t)N+1)*4);
  size_t o_offb = A(((size_t)N+1)*4);
  size_t o_curf = A((size_t)N*4);
  size_t o_curb = A((size_t)N*4);
  size_t o_bsum = A(512*4);
  size_t o_dinv = A((size_t)N*4);
  size_t o_ewf  = A((size_t)E*8);
  size_t o_ewb  = A((size_t)E*8);
  size_t o_cf   = A(8*(size_t)N*4);          // cf1..4, cb1..4
  size_t o_Wt   = A((size_t)512*1152*2);
  size_t o_b2   = A(512*4);
  size_t o_cg   = A(64*4);
  size_t o_T    = A((size_t)NP*1152*2);
  if (p > ws_size) return;  // ws too small: bail (visible as validation failure)

  char* ws = (char*)d_ws;
  int*   cnt_f = (int*)(ws + o_cnt);
  int*   cnt_b = cnt_f + N;
  int*   off_f = (int*)(ws + o_offf);
  int*   off_b = (int*)(ws + o_offb);
  int*   cur_f = (int*)(ws + o_curf);
  int*   cur_b = (int*)(ws + o_curb);
  int*   bsum  = (int*)(ws + o_bsum);
  float* dinv  = (float*)(ws + o_dinv);
  ew_t*  ewf   = (ew_t*)(ws + o_ewf);
  ew_t*  ewb   = (ew_t*)(ws + o_ewb);
  float* cf1   = (float*)(ws + o_cf);
  float* cf2   = cf1 + N; float* cf3 = cf2 + N; float* cf4 = cf3 + N;
  float* cb1   = cf4 + N; float* cb2 = cb1 + N; float* cb3 = cb2 + N; float* cb4 = cb3 + N;
  u16*   Wt2   = (u16*)(ws + o_Wt);
  float* bias2 = (float*)(ws + o_b2);
  int*   cg    = (int*)(ws + o_cg);
  u16*   T     = (u16*)(ws + o_T);
  float* outp  = (float*)d_out;

  const int nbN = (N + 255)/256;
  const int nbE = (E + 255)/256;
  const int nb2N = (2*N + 255)/256;

  // zero-init accumulators + T pad rows
  hipMemsetAsync(cnt_f, 0, 2*(size_t)N*4, stream);
  hipMemsetAsync(cg, 0, 64*4, stream);
  hipMemsetAsync(d_out, 0, (size_t)out_size*4, stream);
  if (NP > N) hipMemsetAsync(T + (size_t)N*1152, 0, (size_t)(NP-N)*1152*2, stream);

  // graph prep
  k_hist<<<nbE,256,0,stream>>>(ei, E, cnt_f, cnt_b);
  k_dinv<<<nbN,256,0,stream>>>(cnt_f, dinv, N);
  k_scanA<<<nbN,256,0,stream>>>(cnt_f, off_f, bsum, N);
  k_scanB<<<1,512,0,stream>>>(bsum, nbN, off_f + N);
  k_scanC<<<nbN,256,0,stream>>>(off_f, bsum, N, cur_f);
  k_scanA<<<nbN,256,0,stream>>>(cnt_b, off_b, bsum, N);
  k_scanB<<<1,512,0,stream>>>(bsum, nbN, off_b + N);
  k_scanC<<<nbN,256,0,stream>>>(off_b, bsum, N, cur_b);
  k_fill<<<nbE,256,0,stream>>>(ei, E, dinv, cur_f, cur_b, ewf, ewb);

  // layer 1 scalar chebyshev
  k_sprop<<<nb2N,256,0,stream>>>(x,   nullptr, cf1,  x,   nullptr, cb1, off_f,ewf, off_b,ewb, N);
  k_sprop<<<nb2N,256,0,stream>>>(cf1, x,       cf2,  cb1, x,       cb2, off_f,ewf, off_b,ewb, N);
  k_sprop<<<nb2N,256,0,stream>>>(cf2, cf1,     cf3,  cb2, cb1,     cb3, off_f,ewf, off_b,ewb, N);
  k_sprop<<<nb2N,256,0,stream>>>(cf3, cf2,     cf4,  cb3, cb2,     cb4, off_f,ewf, off_b,ewb, N);
  k_expand<<<(N+1)/2,256,0,stream>>>(x, cf1,cf2,cf3,cf4, cb1,cb2,cb3,cb4, W1f,b1f,W1b,b1b, T, N);

  // weights for fused GEMM (fragment-tiled)
  k_wprep<<<(512*1152+255)/256,256,0,stream>>>(W2f, W2b, b2f, b2b, Wt2, bias2);

  // layer 2 vector chebyshev: slots 0=h, 1..4=fwd, 5..8=bwd
  const int vb = (2*N*64 + 255)/256;
  k_vprop<<<vb,256,0,stream>>>(T, off_f,ewf, off_b,ewb, 0,1,-1, 0,5,-1, N);
  k_vprop<<<vb,256,0,stream>>>(T, off_f,ewf, off_b,ewb, 1,2, 0, 5,6, 0, N);
  k_vprop<<<vb,256,0,stream>>>(T, off_f,ewf, off_b,ewb, 2,3, 1, 6,7, 5, N);
  k_vprop<<<vb,256,0,stream>>>(T, off_f,ewf, off_b,ewb, 3,4, 2, 7,8, 6, N);

  // pooled GEMM + mean (grid padded to full 8-groups for the XCD pairing map)
  k_count<<<(N+1023)/1024,256,0,stream>>>(bat, cg, N);
  const int gemmGrid = ((NB + 7)/8)*8*2;
  k_gemm<<<gemmGrid,512,0,stream>>>(T, Wt2, bias2, bat, outp, N, NB);
  k_div<<<(out_size+255)/256,256,0,stream>>>(outp, cg, out_size);
}

// Round 12
// 536.150 us; speedup vs baseline: 1.3074x; 1.3074x over previous
//
#include <hip/hip_runtime.h>
#include <hip/hip_bf16.h>

typedef unsigned short u16;
typedef unsigned int u32;
typedef __attribute__((ext_vector_type(4))) float f32x4;
typedef __attribute__((ext_vector_type(8))) short bf16x8;

struct __align__(8) ew_t { int s; float w; };   // packed edge record

#define WLOOP (2.0f/3.0f - 1.0f)      /* -1/3 */
#define WEDGE (-(2.0f/3.0f))          /* -(2/lambda_max) */

__device__ __forceinline__ float bf2f(u16 h){ u32 u = ((u32)h)<<16; float f; __builtin_memcpy(&f,&u,4); return f; }
__device__ __forceinline__ u16 f2bf(float f){ u32 u; __builtin_memcpy(&u,&f,4); u32 r = u + 0x7fffu + ((u>>16)&1u); return (u16)(r>>16); }

__device__ __forceinline__ void async16(u16* lds, const u16* g){
  __builtin_amdgcn_global_load_lds((const __attribute__((address_space(1))) u32*)g,
                                   (__attribute__((address_space(3))) u32*)lds, 16, 0, 0);
}

// ---------------- graph prep ----------------
__global__ void k_hist(const int* __restrict__ ei, int E, int* cntf, int* cntb){
  int e = blockIdx.x*256 + threadIdx.x; if (e>=E) return;
  atomicAdd(&cntf[ei[e]],1); atomicAdd(&cntb[ei[E+e]],1);
}
__global__ void k_dinv(const int* __restrict__ cntf, float* dinv, int N){
  int n = blockIdx.x*256+threadIdx.x; if(n>=N) return;
  int d = cntf[n]; dinv[n] = d>0 ? rsqrtf((float)d) : 0.f;
}
__global__ void k_scanA(const int* __restrict__ cnt, int* excl, int* bsum, int n){
  __shared__ int sh[256]; int i = blockIdx.x*256+threadIdx.x;
  int v = (i<n)? cnt[i]:0; sh[threadIdx.x]=v; __syncthreads();
  for (int off=1; off<256; off<<=1){
    int t = (threadIdx.x>=off)? sh[threadIdx.x-off]:0; __syncthreads();
    sh[threadIdx.x]+=t; __syncthreads();
  }
  if (i<n) excl[i]=sh[threadIdx.x]-v;
  if (threadIdx.x==255) bsum[blockIdx.x]=sh[255];
}
__global__ void k_scanB(int* bsum, int nb, int* total){
  __shared__ int sh[512]; int t = threadIdx.x;
  int v = (t<nb)? bsum[t]:0; sh[t]=v; __syncthreads();
  for(int off=1; off<512; off<<=1){
    int a = (t>=off)? sh[t-off]:0; __syncthreads();
    sh[t]+=a; __syncthreads();
  }
  if (t<nb) bsum[t]=sh[t]-v;
  if (t==511) *total = sh[511];
}
__global__ void k_scanC(int* excl, const int* __restrict__ bsum, int n, int* cur){
  int i = blockIdx.x*256+threadIdx.x; if(i>=n) return;
  int v = excl[i]+bsum[blockIdx.x]; excl[i]=v; cur[i]=v;
}
__global__ void k_fill(const int* __restrict__ ei, int E, const float* __restrict__ dinv,
                       int* curf, int* curb, ew_t* ewf, ew_t* ewb){
  int e = blockIdx.x*256+threadIdx.x; if(e>=E) return;
  int r = ei[e], c = ei[E+e];
  float w = WEDGE * dinv[r]*dinv[c];
  int pf = atomicAdd(&curf[r],1); ewf[pf] = {c, w};
  int pb = atomicAdd(&curb[c],1); ewb[pb] = {r, w};
}

// ---------------- layer 1 (scalar cheb), packed edges, 4-way unrolled (R10) ----------------
__global__ void k_sprop(const float* __restrict__ t1f, const float* __restrict__ t0f, float* df,
                        const float* __restrict__ t1b, const float* __restrict__ t0b, float* db,
                        const int* __restrict__ offf, const ew_t* __restrict__ ewfa,
                        const int* __restrict__ offb, const ew_t* __restrict__ ewba,
                        int N){
  int i = blockIdx.x*256+threadIdx.x;
  int dir = 0; if (i >= N){ i -= N; dir = 1; }
  if (i >= N) return;
  const float* t1; const float* t0; float* d; const int* off; const ew_t* ew;
  if (dir==0){ t1=t1f; t0=t0f; d=df; off=offf; ew=ewfa; }
  else       { t1=t1b; t0=t0b; d=db; off=offb; ew=ewba; }
  float a = WLOOP * t1[i];
  int e = off[i], e1 = off[i+1];
  for (; e+4<=e1; e+=4){
    ew_t p0=ew[e], p1=ew[e+1], p2=ew[e+2], p3=ew[e+3];
    float v0=t1[p0.s], v1=t1[p1.s], v2=t1[p2.s], v3=t1[p3.s];
    a += p0.w*v0 + p1.w*v1 + p2.w*v2 + p3.w*v3;
  }
  for (; e<e1; ++e){ ew_t p=ew[e]; a += p.w*t1[p.s]; }
  d[i] = t0 ? (2.f*a - t0[i]) : a;
}

__global__ void k_expand(const float* __restrict__ x,
   const float* __restrict__ cf1, const float* __restrict__ cf2, const float* __restrict__ cf3, const float* __restrict__ cf4,
   const float* __restrict__ cb1, const float* __restrict__ cb2, const float* __restrict__ cb3, const float* __restrict__ cb4,
   const float* __restrict__ W1f, const float* __restrict__ b1f,
   const float* __restrict__ W1b, const float* __restrict__ b1b,
   u16* __restrict__ T, int N){
  __shared__ float swf[640], swb[640], sbias[128];
  int tid = threadIdx.x;
  for (int i=tid;i<640;i+=256){ swf[i]=W1f[i]; swb[i]=W1b[i]; }
  if (tid<128) sbias[tid]=b1f[tid]+b1b[tid];
  __syncthreads();
  int j = tid & 127; int n = blockIdx.x*2 + (tid>>7);
  if (n>=N) return;
  float xx = x[n];
  float acc = sbias[j] + xx*(swf[j]+swb[j]);
  acc += cf1[n]*swf[128+j]; acc += cf2[n]*swf[256+j]; acc += cf3[n]*swf[384+j]; acc += cf4[n]*swf[512+j];
  acc += cb1[n]*swb[128+j]; acc += cb2[n]*swb[256+j]; acc += cb3[n]*swb[384+j]; acc += cb4[n]*swb[512+j];
  T[(size_t)n*1152 + j] = f2bf(fmaxf(acc,0.f));
}

// ---------------- layer 2 vector props: 4 nodes/wave, 16 lanes/node, dwordx4 rows ----------------
// One gather instruction covers 4 edges (4 rows x 16 lanes x 16B). Edge records are
// 8B broadcast loads per 16-lane group. Predicated to wave-max degree (clamped index,
// zeroed weight, clamped row id -> no NaN, no fault). j-loop unrolled x2 for MLP.
__global__ void k_vprop(u16* __restrict__ T,
   const int* __restrict__ offf, const ew_t* __restrict__ ewfa,
   const int* __restrict__ offb, const ew_t* __restrict__ ewba,
   int ssf, int dsf, int psf, int ssb, int dsb, int psb, int N){
  int gid = blockIdx.x*256 + threadIdx.x;
  int l = threadIdx.x & 63, li = l & 15;
  int nd = (gid>>6)*4 + (l>>4);
  int dir = 0; if (nd >= N){ nd -= N; dir = 1; }
  bool alive = nd < N;
  int wid = alive ? nd : 0;
  const int* off; const ew_t* ew; int ss,ds,ps;
  if (!dir){ off=offf;ew=ewfa;ss=ssf;ds=dsf;ps=psf; }
  else     { off=offb;ew=ewba;ss=ssb;ds=dsb;ps=psb; }

  const u16* Trow = T + (size_t)ss*128 + li*8;      // + row*1152
  bf16x8 sv = *(const bf16x8*)(Trow + (size_t)wid*1152);
  float a[8];
  #pragma unroll
  for (int q=0;q<8;q++) a[q] = WLOOP * bf2f((u16)sv[q]);

  int e0 = alive ? off[wid]   : 0;
  int e1 = alive ? off[wid+1] : 0;
  int deg = e1 - e0;
  int dm = max(deg, __shfl_xor(deg, 16));
  dm = max(dm, __shfl_xor(dm, 32));                 // wave-max degree

  for (int j=0; j<dm; j+=2){
    bool a0v = j   < deg;
    bool a1v = j+1 < deg;
    ew_t p0 = ew[e0 + (a0v ? j   : 0)];
    ew_t p1 = ew[e0 + (a1v ? j+1 : 0)];
    float w0 = a0v ? p0.w : 0.f;
    float w1 = a1v ? p1.w : 0.f;
    int s0 = a0v ? p0.s : wid;
    int s1 = a1v ? p1.s : wid;
    bf16x8 n0 = *(const bf16x8*)(Trow + (size_t)s0*1152);
    bf16x8 n1 = *(const bf16x8*)(Trow + (size_t)s1*1152);
    #pragma unroll
    for (int q=0;q<8;q++) a[q] += w0*bf2f((u16)n0[q]) + w1*bf2f((u16)n1[q]);
  }

  float r[8];
  if (ps >= 0){
    bf16x8 pv = *(const bf16x8*)(T + (size_t)wid*1152 + (size_t)ps*128 + li*8);
    #pragma unroll
    for (int q=0;q<8;q++) r[q] = 2.f*a[q] - bf2f((u16)pv[q]);
  } else {
    #pragma unroll
    for (int q=0;q<8;q++) r[q] = a[q];
  }
  if (alive){
    bf16x8 o;
    #pragma unroll
    for (int q=0;q<8;q++) o[q] = (short)f2bf(r[q]);
    *(bf16x8*)(T + (size_t)wid*1152 + (size_t)ds*128 + li*8) = o;
  }
}

// ---------------- weight prep: fragment-tiled Wt2 ----------------
__global__ void k_wprep(const float* __restrict__ W2f, const float* __restrict__ W2b,
                        const float* __restrict__ b2f, const float* __restrict__ b2b,
                        u16* __restrict__ Wt2, float* __restrict__ bias2){
  int i = blockIdx.x*256+threadIdx.x;
  if (i < 512) bias2[i] = b2f[i]+b2b[i];
  if (i >= 512*1152) return;
  int j = i&7, l = (i>>3)&63, nt = (i>>9)&31, t = i>>14;
  int col = nt*16 + (l&15);
  int k   = t*32 + (l>>4)*8 + j;
  int s2 = k>>7, c = k&127;
  float v;
  if (s2==0)      v = W2f[c*512+col] + W2b[c*512+col];
  else if (s2<5)  v = W2f[(s2*128+c)*512 + col];
  else            v = W2b[((s2-4)*128+c)*512 + col];
  Wt2[i] = f2bf(v);
}

// ---------------- pooled GEMM (R10 exact): BM=128, BN=256, 8 waves, 2 blocks/CU ----------------
__global__ __launch_bounds__(512, 4) void k_gemm(const u16* __restrict__ T, const u16* __restrict__ Wt2,
                        const float* __restrict__ bias2, const int* __restrict__ batch,
                        float* __restrict__ outp, int Mvalid, int NB){
  int bid = blockIdx.x;
  int r8 = bid & 7, q = bid >> 3;
  int bn = q & 1, bm = (q >> 1)*8 + r8;
  if (bm >= NB) return;
  __shared__ u16 Al[2][128*32];     // 8KB per buf
  int tid = threadIdx.x, w = tid>>6, l = tid&63;
  int wr = w>>2, wc = w&3;          // wave grid 2 x 4 -> per-wave 64 rows x 64 cols
  int hi = l>>4, lo = l&15;

  f32x4 acc[4][4];
  #pragma unroll
  for (int m=0;m<4;m++)
    #pragma unroll
    for (int n=0;n<4;n++){ acc[m][n][0]=0.f; acc[m][n][1]=0.f; acc[m][n][2]=0.f; acc[m][n][3]=0.f; }

  // A staging: thread -> (row = tid>>2, chunk slot = tid&3); source chunk pre-swizzled
  int sr = tid>>2, sp = tid&3;
  int csrc = ((sp ^ ((sr>>1)&3)))*8;
  const u16* asrc = T + (size_t)(bm*128 + sr)*1152 + csrc;
  const int adst = tid*8;                                  // linear dest
  // A fragment read base: same XOR on read side
  int rsw = (hi ^ ((lo>>1)&3))*8;
  const int abase = (wr*64 + lo)*32 + rsw;                 // + m*512
  // B fragment base: ntile = bn*16 + wc*4 + n; frag(t,ntile) at (t*32+ntile)*512 u16
  const u16* bsrc = Wt2 + ((size_t)(bn*16 + wc*4)*64 + l)*8;   // + t*16384 + n*512

  #define LOADB(dst, t_) do { \
    _Pragma("unroll") \
    for (int n_=0;n_<4;n_++) dst[n_] = *(const bf16x8*)(bsrc + (size_t)(t_)*16384 + n_*512); \
  } while(0)

  bf16x8 be[4], bo[4];
  async16(&Al[0][adst], asrc);
  LOADB(be, 0);

  for (int t=0; t<36; t+=2){            // K = 1152 = 36*32, unrolled x2
    // ---- even: tile t from Al[0] x be ----
    if (t < 35){
      async16(&Al[1][adst], asrc + (t+1)*32);
      LOADB(bo, t+1);
      asm volatile("s_waitcnt vmcnt(5)" ::: "memory");   // stage(t)+be(t) retired
    } else {
      asm volatile("s_waitcnt vmcnt(0)" ::: "memory");
    }
    asm volatile("s_barrier" ::: "memory");
    __builtin_amdgcn_s_setprio(1);
    #pragma unroll
    for (int m=0;m<4;m++){
      bf16x8 af = *(const bf16x8*)&Al[0][abase + m*512];
      #pragma unroll
      for (int n=0;n<4;n++)
        acc[m][n] = __builtin_amdgcn_mfma_f32_16x16x32_bf16(af, be[n], acc[m][n], 0, 0, 0);
    }
    __builtin_amdgcn_s_setprio(0);
    asm volatile("s_barrier" ::: "memory");
    // ---- odd: tile t+1 from Al[1] x bo ----
    if (t+2 < 36){
      async16(&Al[0][adst], asrc + (t+2)*32);
      LOADB(be, t+2);
      asm volatile("s_waitcnt vmcnt(5)" ::: "memory");   // stage(t+1)+bo(t+1) retired
    } else {
      asm volatile("s_waitcnt vmcnt(0)" ::: "memory");
    }
    asm volatile("s_barrier" ::: "memory");
    __builtin_amdgcn_s_setprio(1);
    #pragma unroll
    for (int m=0;m<4;m++){
      bf16x8 af = *(const bf16x8*)&Al[1][abase + m*512];
      #pragma unroll
      for (int n=0;n<4;n++)
        acc[m][n] = __builtin_amdgcn_mfma_f32_16x16x32_bf16(af, bo[n], acc[m][n], 0, 0, 0);
    }
    __builtin_amdgcn_s_setprio(0);
    asm volatile("s_barrier" ::: "memory");
  }
  #undef LOADB

  // epilogue: bias + relu + pooled segment-sum (batch sorted -> run-length over 16 rows)
  int bg[16];
  #pragma unroll
  for (int m=0;m<4;m++)
    #pragma unroll
    for (int j2=0;j2<4;j2++){
      int row = bm*128 + wr*64 + m*16 + hi*4 + j2;
      bg[m*4+j2] = (row < Mvalid) ? batch[row] : -1;
    }
  #pragma unroll
  for (int n=0;n<4;n++){
    int col = bn*256 + wc*64 + n*16 + lo;
    float bc = bias2[col];
    int cg2 = -1; float ssum = 0.f;
    #pragma unroll
    for (int idx=0; idx<16; idx++){
      int g = bg[idx];
      if (g >= 0){
        float val = fmaxf(acc[idx>>2][n][idx&3] + bc, 0.f);
        if (g != cg2){ if (cg2 >= 0) atomicAdd(&outp[(cg2<<9) + col], ssum); cg2 = g; ssum = 0.f; }
        ssum += val;
      }
    }
    if (cg2 >= 0) atomicAdd(&outp[(cg2<<9) + col], ssum);
  }
}

// per-block LDS histogram: ~200 global atomics total instead of 100k
__global__ void k_count(const int* __restrict__ batch, int* cg, int N){
  __shared__ int sh[64];
  int t = threadIdx.x;
  if (t < 64) sh[t] = 0;
  __syncthreads();
  int base = blockIdx.x*1024;
  #pragma unroll
  for (int i = base + t; i < base + 1024; i += 256){
    if (i < N) atomicAdd(&sh[batch[i]], 1);
  }
  __syncthreads();
  if (t < 64){ int v = sh[t]; if (v) atomicAdd(&cg[t], v); }
}

__global__ void k_div(float* out, const int* __restrict__ cg, int total){
  int i = blockIdx.x*256+threadIdx.x; if (i>=total) return;
  int g = i>>9; out[i] /= fmaxf((float)cg[g], 1.f);
}

extern "C" void kernel_launch(void* const* d_in, const int* in_sizes, int n_in,
                              void* d_out, int out_size, void* d_ws, size_t ws_size,
                              hipStream_t stream) {
  const float* x   = (const float*)d_in[0];
  const int*   ei  = (const int*)d_in[1];
  const int*   bat = (const int*)d_in[2];
  const float* W1f = (const float*)d_in[3];
  const float* b1f = (const float*)d_in[4];
  const float* W1b = (const float*)d_in[5];
  const float* b1b = (const float*)d_in[6];
  const float* W2f = (const float*)d_in[7];
  const float* b2f = (const float*)d_in[8];
  const float* W2b = (const float*)d_in[9];
  const float* b2b = (const float*)d_in[10];

  const int N  = in_sizes[0];
  const int E  = in_sizes[1] / 2;
  const int NP = ((N + 127)/128)*128;
  const int NB = NP/128;

  // ---- ws layout ----
  size_t p = 0;
  auto A = [&](size_t sz){ size_t r = p; p += (sz + 255) & ~(size_t)255; return r; };
  size_t o_cnt  = A(2*(size_t)N*4);          // cnt_f | cnt_b
  size_t o_offf = A(((size_t)N+1)*4);
  size_t o_offb = A(((size_t)N+1)*4);
  size_t o_curf = A((size_t)N*4);
  size_t o_curb = A((size_t)N*4);
  size_t o_bsum = A(512*4);
  size_t o_dinv = A((size_t)N*4);
  size_t o_ewf  = A((size_t)E*8);
  size_t o_ewb  = A((size_t)E*8);
  size_t o_cf   = A(8*(size_t)N*4);          // cf1..4, cb1..4
  size_t o_Wt   = A((size_t)512*1152*2);
  size_t o_b2   = A(512*4);
  size_t o_cg   = A(64*4);
  size_t o_T    = A((size_t)NP*1152*2);
  if (p > ws_size) return;  // ws too small: bail (visible as validation failure)

  char* ws = (char*)d_ws;
  int*   cnt_f = (int*)(ws + o_cnt);
  int*   cnt_b = cnt_f + N;
  int*   off_f = (int*)(ws + o_offf);
  int*   off_b = (int*)(ws + o_offb);
  int*   cur_f = (int*)(ws + o_curf);
  int*   cur_b = (int*)(ws + o_curb);
  int*   bsum  = (int*)(ws + o_bsum);
  float* dinv  = (float*)(ws + o_dinv);
  ew_t*  ewf   = (ew_t*)(ws + o_ewf);
  ew_t*  ewb   = (ew_t*)(ws + o_ewb);
  float* cf1   = (float*)(ws + o_cf);
  float* cf2   = cf1 + N; float* cf3 = cf2 + N; float* cf4 = cf3 + N;
  float* cb1   = cf4 + N; float* cb2 = cb1 + N; float* cb3 = cb2 + N; float* cb4 = cb3 + N;
  u16*   Wt2   = (u16*)(ws + o_Wt);
  float* bias2 = (float*)(ws + o_b2);
  int*   cg    = (int*)(ws + o_cg);
  u16*   T     = (u16*)(ws + o_T);
  float* outp  = (float*)d_out;

  const int nbN = (N + 255)/256;
  const int nbE = (E + 255)/256;
  const int nb2N = (2*N + 255)/256;

  // zero-init accumulators + T pad rows
  hipMemsetAsync(cnt_f, 0, 2*(size_t)N*4, stream);
  hipMemsetAsync(cg, 0, 64*4, stream);
  hipMemsetAsync(d_out, 0, (size_t)out_size*4, stream);
  if (NP > N) hipMemsetAsync(T + (size_t)N*1152, 0, (size_t)(NP-N)*1152*2, stream);

  // graph prep
  k_hist<<<nbE,256,0,stream>>>(ei, E, cnt_f, cnt_b);
  k_dinv<<<nbN,256,0,stream>>>(cnt_f, dinv, N);
  k_scanA<<<nbN,256,0,stream>>>(cnt_f, off_f, bsum, N);
  k_scanB<<<1,512,0,stream>>>(bsum, nbN, off_f + N);
  k_scanC<<<nbN,256,0,stream>>>(off_f, bsum, N, cur_f);
  k_scanA<<<nbN,256,0,stream>>>(cnt_b, off_b, bsum, N);
  k_scanB<<<1,512,0,stream>>>(bsum, nbN, off_b + N);
  k_scanC<<<nbN,256,0,stream>>>(off_b, bsum, N, cur_b);
  k_fill<<<nbE,256,0,stream>>>(ei, E, dinv, cur_f, cur_b, ewf, ewb);

  // layer 1 scalar chebyshev
  k_sprop<<<nb2N,256,0,stream>>>(x,   nullptr, cf1,  x,   nullptr, cb1, off_f,ewf, off_b,ewb, N);
  k_sprop<<<nb2N,256,0,stream>>>(cf1, x,       cf2,  cb1, x,       cb2, off_f,ewf, off_b,ewb, N);
  k_sprop<<<nb2N,256,0,stream>>>(cf2, cf1,     cf3,  cb2, cb1,     cb3, off_f,ewf, off_b,ewb, N);
  k_sprop<<<nb2N,256,0,stream>>>(cf3, cf2,     cf4,  cb3, cb2,     cb4, off_f,ewf, off_b,ewb, N);
  k_expand<<<(N+1)/2,256,0,stream>>>(x, cf1,cf2,cf3,cf4, cb1,cb2,cb3,cb4, W1f,b1f,W1b,b1b, T, N);

  // weights for fused GEMM (fragment-tiled)
  k_wprep<<<(512*1152+255)/256,256,0,stream>>>(W2f, W2b, b2f, b2b, Wt2, bias2);

  // layer 2 vector chebyshev: slots 0=h, 1..4=fwd, 5..8=bwd (4 nodes/wave, 16 lanes/node)
  const int vb = (2*N*16 + 255)/256;
  k_vprop<<<vb,256,0,stream>>>(T, off_f,ewf, off_b,ewb, 0,1,-1, 0,5,-1, N);
  k_vprop<<<vb,256,0,stream>>>(T, off_f,ewf, off_b,ewb, 1,2, 0, 5,6, 0, N);
  k_vprop<<<vb,256,0,stream>>>(T, off_f,ewf, off_b,ewb, 2,3, 1, 6,7, 5, N);
  k_vprop<<<vb,256,0,stream>>>(T, off_f,ewf, off_b,ewb, 3,4, 2, 7,8, 6, N);

  // pooled GEMM + mean (grid padded to full 8-groups for the XCD pairing map)
  k_count<<<(N+1023)/1024,256,0,stream>>>(bat, cg, N);
  const int gemmGrid = ((NB + 7)/8)*8*2;
  k_gemm<<<gemmGrid,512,0,stream>>>(T, Wt2, bias2, bat, outp, N, NB);
  k_div<<<(out_size+255)/256,256,0,stream>>>(outp, cg, out_size);
}

// Round 13
// 524.674 us; speedup vs baseline: 1.3360x; 1.0219x over previous
//
#include <hip/hip_runtime.h>
#include <hip/hip_bf16.h>

typedef unsigned short u16;
typedef unsigned int u32;
typedef __attribute__((ext_vector_type(4))) float f32x4;
typedef __attribute__((ext_vector_type(8))) short bf16x8;

struct __align__(8) ew_t { int s; float w; };   // packed edge record

#define WLOOP (2.0f/3.0f - 1.0f)      /* -1/3 */
#define WEDGE (-(2.0f/3.0f))          /* -(2/lambda_max) */

__device__ __forceinline__ float bf2f(u16 h){ u32 u = ((u32)h)<<16; float f; __builtin_memcpy(&f,&u,4); return f; }
__device__ __forceinline__ u16 f2bf(float f){ u32 u; __builtin_memcpy(&u,&f,4); u32 r = u + 0x7fffu + ((u>>16)&1u); return (u16)(r>>16); }

__device__ __forceinline__ void async16(u16* lds, const u16* g){
  __builtin_amdgcn_global_load_lds((const __attribute__((address_space(1))) u32*)g,
                                   (__attribute__((address_space(3))) u32*)lds, 16, 0, 0);
}

// ---------------- graph prep ----------------
__global__ void k_hist(const int* __restrict__ ei, int E, int* cntf, int* cntb){
  int e = blockIdx.x*256 + threadIdx.x; if (e>=E) return;
  atomicAdd(&cntf[ei[e]],1); atomicAdd(&cntb[ei[E+e]],1);
}
__global__ void k_dinv(const int* __restrict__ cntf, float* dinv, int N){
  int n = blockIdx.x*256+threadIdx.x; if(n>=N) return;
  int d = cntf[n]; dinv[n] = d>0 ? rsqrtf((float)d) : 0.f;
}
__global__ void k_scanA(const int* __restrict__ cnt, int* excl, int* bsum, int n){
  __shared__ int sh[256]; int i = blockIdx.x*256+threadIdx.x;
  int v = (i<n)? cnt[i]:0; sh[threadIdx.x]=v; __syncthreads();
  for (int off=1; off<256; off<<=1){
    int t = (threadIdx.x>=off)? sh[threadIdx.x-off]:0; __syncthreads();
    sh[threadIdx.x]+=t; __syncthreads();
  }
  if (i<n) excl[i]=sh[threadIdx.x]-v;
  if (threadIdx.x==255) bsum[blockIdx.x]=sh[255];
}
__global__ void k_scanB(int* bsum, int nb, int* total){
  __shared__ int sh[512]; int t = threadIdx.x;
  int v = (t<nb)? bsum[t]:0; sh[t]=v; __syncthreads();
  for(int off=1; off<512; off<<=1){
    int a = (t>=off)? sh[t-off]:0; __syncthreads();
    sh[t]+=a; __syncthreads();
  }
  if (t<nb) bsum[t]=sh[t]-v;
  if (t==511) *total = sh[511];
}
__global__ void k_scanC(int* excl, const int* __restrict__ bsum, int n, int* cur){
  int i = blockIdx.x*256+threadIdx.x; if(i>=n) return;
  int v = excl[i]+bsum[blockIdx.x]; excl[i]=v; cur[i]=v;
}
__global__ void k_fill(const int* __restrict__ ei, int E, const float* __restrict__ dinv,
                       int* curf, int* curb, ew_t* ewf, ew_t* ewb){
  int e = blockIdx.x*256+threadIdx.x; if(e>=E) return;
  int r = ei[e], c = ei[E+e];
  float w = WEDGE * dinv[r]*dinv[c];
  int pf = atomicAdd(&curf[r],1); ewf[pf] = {c, w};
  int pb = atomicAdd(&curb[c],1); ewb[pb] = {r, w};
}

// ---------------- layer 1 (scalar cheb), packed edges, 4-way unrolled (R10) ----------------
__global__ void k_sprop(const float* __restrict__ t1f, const float* __restrict__ t0f, float* df,
                        const float* __restrict__ t1b, const float* __restrict__ t0b, float* db,
                        const int* __restrict__ offf, const ew_t* __restrict__ ewfa,
                        const int* __restrict__ offb, const ew_t* __restrict__ ewba,
                        int N){
  int i = blockIdx.x*256+threadIdx.x;
  int dir = 0; if (i >= N){ i -= N; dir = 1; }
  if (i >= N) return;
  const float* t1; const float* t0; float* d; const int* off; const ew_t* ew;
  if (dir==0){ t1=t1f; t0=t0f; d=df; off=offf; ew=ewfa; }
  else       { t1=t1b; t0=t0b; d=db; off=offb; ew=ewba; }
  float a = WLOOP * t1[i];
  int e = off[i], e1 = off[i+1];
  for (; e+4<=e1; e+=4){
    ew_t p0=ew[e], p1=ew[e+1], p2=ew[e+2], p3=ew[e+3];
    float v0=t1[p0.s], v1=t1[p1.s], v2=t1[p2.s], v3=t1[p3.s];
    a += p0.w*v0 + p1.w*v1 + p2.w*v2 + p3.w*v3;
  }
  for (; e<e1; ++e){ ew_t p=ew[e]; a += p.w*t1[p.s]; }
  d[i] = t0 ? (2.f*a - t0[i]) : a;
}

__global__ void k_expand(const float* __restrict__ x,
   const float* __restrict__ cf1, const float* __restrict__ cf2, const float* __restrict__ cf3, const float* __restrict__ cf4,
   const float* __restrict__ cb1, const float* __restrict__ cb2, const float* __restrict__ cb3, const float* __restrict__ cb4,
   const float* __restrict__ W1f, const float* __restrict__ b1f,
   const float* __restrict__ W1b, const float* __restrict__ b1b,
   u16* __restrict__ T, int N){
  __shared__ float swf[640], swb[640], sbias[128];
  int tid = threadIdx.x;
  for (int i=tid;i<640;i+=256){ swf[i]=W1f[i]; swb[i]=W1b[i]; }
  if (tid<128) sbias[tid]=b1f[tid]+b1b[tid];
  __syncthreads();
  int j = tid & 127; int n = blockIdx.x*2 + (tid>>7);
  if (n>=N) return;
  float xx = x[n];
  float acc = sbias[j] + xx*(swf[j]+swb[j]);
  acc += cf1[n]*swf[128+j]; acc += cf2[n]*swf[256+j]; acc += cf3[n]*swf[384+j]; acc += cf4[n]*swf[512+j];
  acc += cb1[n]*swb[128+j]; acc += cb2[n]*swb[256+j]; acc += cb3[n]*swb[384+j]; acc += cb4[n]*swb[512+j];
  T[(size_t)n*1152 + j] = f2bf(fmaxf(acc,0.f));
}

// ---------------- layer 2 vector props: 4 nodes/wave, 16 lanes/node, dwordx4 rows (R12) ----------------
__global__ void k_vprop(u16* __restrict__ T,
   const int* __restrict__ offf, const ew_t* __restrict__ ewfa,
   const int* __restrict__ offb, const ew_t* __restrict__ ewba,
   int ssf, int dsf, int psf, int ssb, int dsb, int psb, int N){
  int gid = blockIdx.x*256 + threadIdx.x;
  int l = threadIdx.x & 63, li = l & 15;
  int nd = (gid>>6)*4 + (l>>4);
  int dir = 0; if (nd >= N){ nd -= N; dir = 1; }
  bool alive = nd < N;
  int wid = alive ? nd : 0;
  const int* off; const ew_t* ew; int ss,ds,ps;
  if (!dir){ off=offf;ew=ewfa;ss=ssf;ds=dsf;ps=psf; }
  else     { off=offb;ew=ewba;ss=ssb;ds=dsb;ps=psb; }

  const u16* Trow = T + (size_t)ss*128 + li*8;      // + row*1152
  bf16x8 sv = *(const bf16x8*)(Trow + (size_t)wid*1152);
  float a[8];
  #pragma unroll
  for (int q=0;q<8;q++) a[q] = WLOOP * bf2f((u16)sv[q]);

  int e0 = alive ? off[wid]   : 0;
  int e1 = alive ? off[wid+1] : 0;
  int deg = e1 - e0;
  int dm = max(deg, __shfl_xor(deg, 16));
  dm = max(dm, __shfl_xor(dm, 32));                 // wave-max degree

  for (int j=0; j<dm; j+=2){
    bool a0v = j   < deg;
    bool a1v = j+1 < deg;
    ew_t p0 = ew[e0 + (a0v ? j   : 0)];
    ew_t p1 = ew[e0 + (a1v ? j+1 : 0)];
    float w0 = a0v ? p0.w : 0.f;
    float w1 = a1v ? p1.w : 0.f;
    int s0 = a0v ? p0.s : wid;
    int s1 = a1v ? p1.s : wid;
    bf16x8 n0 = *(const bf16x8*)(Trow + (size_t)s0*1152);
    bf16x8 n1 = *(const bf16x8*)(Trow + (size_t)s1*1152);
    #pragma unroll
    for (int q=0;q<8;q++) a[q] += w0*bf2f((u16)n0[q]) + w1*bf2f((u16)n1[q]);
  }

  float r[8];
  if (ps >= 0){
    bf16x8 pv = *(const bf16x8*)(T + (size_t)wid*1152 + (size_t)ps*128 + li*8);
    #pragma unroll
    for (int q=0;q<8;q++) r[q] = 2.f*a[q] - bf2f((u16)pv[q]);
  } else {
    #pragma unroll
    for (int q=0;q<8;q++) r[q] = a[q];
  }
  if (alive){
    bf16x8 o;
    #pragma unroll
    for (int q=0;q<8;q++) o[q] = (short)f2bf(r[q]);
    *(bf16x8*)(T + (size_t)wid*1152 + (size_t)ds*128 + li*8) = o;
  }
}

// ---------------- weight prep: fragment-tiled Wt2 ----------------
__global__ void k_wprep(const float* __restrict__ W2f, const float* __restrict__ W2b,
                        const float* __restrict__ b2f, const float* __restrict__ b2b,
                        u16* __restrict__ Wt2, float* __restrict__ bias2){
  int i = blockIdx.x*256+threadIdx.x;
  if (i < 512) bias2[i] = b2f[i]+b2b[i];
  if (i >= 512*1152) return;
  int j = i&7, l = (i>>3)&63, nt = (i>>9)&31, t = i>>14;
  int col = nt*16 + (l&15);
  int k   = t*32 + (l>>4)*8 + j;
  int s2 = k>>7, c = k&127;
  float v;
  if (s2==0)      v = W2f[c*512+col] + W2b[c*512+col];
  else if (s2<5)  v = W2f[(s2*128+c)*512 + col];
  else            v = W2b[((s2-4)*128+c)*512 + col];
  Wt2[i] = f2bf(v);
}

// ---------------- pooled GEMM: BM=64, BN=256, 256 thr (4 waves), 8 blocks/CU target ----------------
// Same R10 schedule (vmcnt(5), 2 raw barriers, setprio; counts identical: 1 stage + 4 B-frags)
// but 4-wave barrier groups and ~4x the independent blocks per CU (VGPR ~60, LDS 8KB).
__global__ __launch_bounds__(256, 4) void k_gemm(const u16* __restrict__ T, const u16* __restrict__ Wt2,
                        const float* __restrict__ bias2, const int* __restrict__ batch,
                        float* __restrict__ outp, int Mvalid, int NB){
  int bid = blockIdx.x;
  int r8 = bid & 7, q = bid >> 3;
  int bn = q & 1, bm = (q >> 1)*8 + r8;
  if (bm >= NB) return;
  __shared__ u16 Al[2][64*32];      // 4KB per buf
  int tid = threadIdx.x, w = tid>>6, l = tid&63;
  int wc = w;                       // wave grid 1 x 4 -> per-wave 64 rows x 64 cols
  int hi = l>>4, lo = l&15;

  f32x4 acc[4][4];
  #pragma unroll
  for (int m=0;m<4;m++)
    #pragma unroll
    for (int n=0;n<4;n++){ acc[m][n][0]=0.f; acc[m][n][1]=0.f; acc[m][n][2]=0.f; acc[m][n][3]=0.f; }

  // A staging: thread -> (row = tid>>2, chunk slot = tid&3); source chunk pre-swizzled
  int sr = tid>>2, sp = tid&3;
  int csrc = ((sp ^ ((sr>>1)&3)))*8;
  const u16* asrc = T + (size_t)(bm*64 + sr)*1152 + csrc;
  const int adst = tid*8;                                  // linear dest (256*16B = 4KB tile)
  // A fragment read base: same XOR on read side
  int rsw = (hi ^ ((lo>>1)&3))*8;
  const int abase = lo*32 + rsw;                           // + m*512
  // B fragment base: ntile = bn*16 + wc*4 + n; frag(t,ntile) at (t*32+ntile)*512 u16
  const u16* bsrc = Wt2 + ((size_t)(bn*16 + wc*4)*64 + l)*8;   // + t*16384 + n*512

  #define LOADB(dst, t_) do { \
    _Pragma("unroll") \
    for (int n_=0;n_<4;n_++) dst[n_] = *(const bf16x8*)(bsrc + (size_t)(t_)*16384 + n_*512); \
  } while(0)

  bf16x8 be[4], bo[4];
  async16(&Al[0][adst], asrc);
  LOADB(be, 0);

  for (int t=0; t<36; t+=2){            // K = 1152 = 36*32, unrolled x2
    // ---- even: tile t from Al[0] x be ----
    if (t < 35){
      async16(&Al[1][adst], asrc + (t+1)*32);
      LOADB(bo, t+1);
      asm volatile("s_waitcnt vmcnt(5)" ::: "memory");   // stage(t)+be(t) retired
    } else {
      asm volatile("s_waitcnt vmcnt(0)" ::: "memory");
    }
    asm volatile("s_barrier" ::: "memory");
    __builtin_amdgcn_s_setprio(1);
    #pragma unroll
    for (int m=0;m<4;m++){
      bf16x8 af = *(const bf16x8*)&Al[0][abase + m*512];
      #pragma unroll
      for (int n=0;n<4;n++)
        acc[m][n] = __builtin_amdgcn_mfma_f32_16x16x32_bf16(af, be[n], acc[m][n], 0, 0, 0);
    }
    __builtin_amdgcn_s_setprio(0);
    asm volatile("s_barrier" ::: "memory");
    // ---- odd: tile t+1 from Al[1] x bo ----
    if (t+2 < 36){
      async16(&Al[0][adst], asrc + (t+2)*32);
      LOADB(be, t+2);
      asm volatile("s_waitcnt vmcnt(5)" ::: "memory");   // stage(t+1)+bo(t+1) retired
    } else {
      asm volatile("s_waitcnt vmcnt(0)" ::: "memory");
    }
    asm volatile("s_barrier" ::: "memory");
    __builtin_amdgcn_s_setprio(1);
    #pragma unroll
    for (int m=0;m<4;m++){
      bf16x8 af = *(const bf16x8*)&Al[1][abase + m*512];
      #pragma unroll
      for (int n=0;n<4;n++)
        acc[m][n] = __builtin_amdgcn_mfma_f32_16x16x32_bf16(af, bo[n], acc[m][n], 0, 0, 0);
    }
    __builtin_amdgcn_s_setprio(0);
    asm volatile("s_barrier" ::: "memory");
  }
  #undef LOADB

  // epilogue: bias + relu + pooled segment-sum (batch sorted -> run-length over 16 rows)
  int bg[16];
  #pragma unroll
  for (int m=0;m<4;m++)
    #pragma unroll
    for (int j2=0;j2<4;j2++){
      int row = bm*64 + m*16 + hi*4 + j2;
      bg[m*4+j2] = (row < Mvalid) ? batch[row] : -1;
    }
  #pragma unroll
  for (int n=0;n<4;n++){
    int col = bn*256 + wc*64 + n*16 + lo;
    float bc = bias2[col];
    int cg2 = -1; float ssum = 0.f;
    #pragma unroll
    for (int idx=0; idx<16; idx++){
      int g = bg[idx];
      if (g >= 0){
        float val = fmaxf(acc[idx>>2][n][idx&3] + bc, 0.f);
        if (g != cg2){ if (cg2 >= 0) atomicAdd(&outp[(cg2<<9) + col], ssum); cg2 = g; ssum = 0.f; }
        ssum += val;
      }
    }
    if (cg2 >= 0) atomicAdd(&outp[(cg2<<9) + col], ssum);
  }
}

// per-block LDS histogram: ~200 global atomics total instead of 100k
__global__ void k_count(const int* __restrict__ batch, int* cg, int N){
  __shared__ int sh[64];
  int t = threadIdx.x;
  if (t < 64) sh[t] = 0;
  __syncthreads();
  int base = blockIdx.x*1024;
  #pragma unroll
  for (int i = base + t; i < base + 1024; i += 256){
    if (i < N) atomicAdd(&sh[batch[i]], 1);
  }
  __syncthreads();
  if (t < 64){ int v = sh[t]; if (v) atomicAdd(&cg[t], v); }
}

__global__ void k_div(float* out, const int* __restrict__ cg, int total){
  int i = blockIdx.x*256+threadIdx.x; if (i>=total) return;
  int g = i>>9; out[i] /= fmaxf((float)cg[g], 1.f);
}

extern "C" void kernel_launch(void* const* d_in, const int* in_sizes, int n_in,
                              void* d_out, int out_size, void* d_ws, size_t ws_size,
                              hipStream_t stream) {
  const float* x   = (const float*)d_in[0];
  const int*   ei  = (const int*)d_in[1];
  const int*   bat = (const int*)d_in[2];
  const float* W1f = (const float*)d_in[3];
  const float* b1f = (const float*)d_in[4];
  const float* W1b = (const float*)d_in[5];
  const float* b1b = (const float*)d_in[6];
  const float* W2f = (const float*)d_in[7];
  const float* b2f = (const float*)d_in[8];
  const float* W2b = (const float*)d_in[9];
  const float* b2b = (const float*)d_in[10];

  const int N  = in_sizes[0];
  const int E  = in_sizes[1] / 2;
  const int NP = ((N + 127)/128)*128;
  const int NB = ((N + 63)/64);            // 64-row tiles (pad rows zeroed below)

  // ---- ws layout ----
  size_t p = 0;
  auto A = [&](size_t sz){ size_t r = p; p += (sz + 255) & ~(size_t)255; return r; };
  size_t o_cnt  = A(2*(size_t)N*4);          // cnt_f | cnt_b
  size_t o_offf = A(((size_t)N+1)*4);
  size_t o_offb = A(((size_t)N+1)*4);
  size_t o_curf = A((size_t)N*4);
  size_t o_curb = A((size_t)N*4);
  size_t o_bsum = A(512*4);
  size_t o_dinv = A((size_t)N*4);
  size_t o_ewf  = A((size_t)E*8);
  size_t o_ewb  = A((size_t)E*8);
  size_t o_cf   = A(8*(size_t)N*4);          // cf1..4, cb1..4
  size_t o_Wt   = A((size_t)512*1152*2);
  size_t o_b2   = A(512*4);
  size_t o_cg   = A(64*4);
  size_t o_T    = A((size_t)NP*1152*2);
  if (p > ws_size) return;  // ws too small: bail (visible as validation failure)

  char* ws = (char*)d_ws;
  int*   cnt_f = (int*)(ws + o_cnt);
  int*   cnt_b = cnt_f + N;
  int*   off_f = (int*)(ws + o_offf);
  int*   off_b = (int*)(ws + o_offb);
  int*   cur_f = (int*)(ws + o_curf);
  int*   cur_b = (int*)(ws + o_curb);
  int*   bsum  = (int*)(ws + o_bsum);
  float* dinv  = (float*)(ws + o_dinv);
  ew_t*  ewf   = (ew_t*)(ws + o_ewf);
  ew_t*  ewb   = (ew_t*)(ws + o_ewb);
  float* cf1   = (float*)(ws + o_cf);
  float* cf2   = cf1 + N; float* cf3 = cf2 + N; float* cf4 = cf3 + N;
  float* cb1   = cf4 + N; float* cb2 = cb1 + N; float* cb3 = cb2 + N; float* cb4 = cb3 + N;
  u16*   Wt2   = (u16*)(ws + o_Wt);
  float* bias2 = (float*)(ws + o_b2);
  int*   cg    = (int*)(ws + o_cg);
  u16*   T     = (u16*)(ws + o_T);
  float* outp  = (float*)d_out;

  const int nbN = (N + 255)/256;
  const int nbE = (E + 255)/256;
  const int nb2N = (2*N + 255)/256;

  // zero-init accumulators + T pad rows
  hipMemsetAsync(cnt_f, 0, 2*(size_t)N*4, stream);
  hipMemsetAsync(cg, 0, 64*4, stream);
  hipMemsetAsync(d_out, 0, (size_t)out_size*4, stream);
  if (NP > N) hipMemsetAsync(T + (size_t)N*1152, 0, (size_t)(NP-N)*1152*2, stream);

  // graph prep
  k_hist<<<nbE,256,0,stream>>>(ei, E, cnt_f, cnt_b);
  k_dinv<<<nbN,256,0,stream>>>(cnt_f, dinv, N);
  k_scanA<<<nbN,256,0,stream>>>(cnt_f, off_f, bsum, N);
  k_scanB<<<1,512,0,stream>>>(bsum, nbN, off_f + N);
  k_scanC<<<nbN,256,0,stream>>>(off_f, bsum, N, cur_f);
  k_scanA<<<nbN,256,0,stream>>>(cnt_b, off_b, bsum, N);
  k_scanB<<<1,512,0,stream>>>(bsum, nbN, off_b + N);
  k_scanC<<<nbN,256,0,stream>>>(off_b, bsum, N, cur_b);
  k_fill<<<nbE,256,0,stream>>>(ei, E, dinv, cur_f, cur_b, ewf, ewb);

  // layer 1 scalar chebyshev
  k_sprop<<<nb2N,256,0,stream>>>(x,   nullptr, cf1,  x,   nullptr, cb1, off_f,ewf, off_b,ewb, N);
  k_sprop<<<nb2N,256,0,stream>>>(cf1, x,       cf2,  cb1, x,       cb2, off_f,ewf, off_b,ewb, N);
  k_sprop<<<nb2N,256,0,stream>>>(cf2, cf1,     cf3,  cb2, cb1,     cb3, off_f,ewf, off_b,ewb, N);
  k_sprop<<<nb2N,256,0,stream>>>(cf3, cf2,     cf4,  cb3, cb2,     cb4, off_f,ewf, off_b,ewb, N);
  k_expand<<<(N+1)/2,256,0,stream>>>(x, cf1,cf2,cf3,cf4, cb1,cb2,cb3,cb4, W1f,b1f,W1b,b1b, T, N);

  // weights for fused GEMM (fragment-tiled)
  k_wprep<<<(512*1152+255)/256,256,0,stream>>>(W2f, W2b, b2f, b2b, Wt2, bias2);

  // layer 2 vector chebyshev: slots 0=h, 1..4=fwd, 5..8=bwd (4 nodes/wave, 16 lanes/node)
  const int vb = (2*N*16 + 255)/256;
  k_vprop<<<vb,256,0,stream>>>(T, off_f,ewf, off_b,ewb, 0,1,-1, 0,5,-1, N);
  k_vprop<<<vb,256,0,stream>>>(T, off_f,ewf, off_b,ewb, 1,2, 0, 5,6, 0, N);
  k_vprop<<<vb,256,0,stream>>>(T, off_f,ewf, off_b,ewb, 2,3, 1, 6,7, 5, N);
  k_vprop<<<vb,256,0,stream>>>(T, off_f,ewf, off_b,ewb, 3,4, 2, 7,8, 6, N);

  // pooled GEMM + mean (grid padded to full 8-groups for the XCD pairing map)
  k_count<<<(N+1023)/1024,256,0,stream>>>(bat, cg, N);
  const int gemmGrid = ((NB + 7)/8)*8*2;
  k_gemm<<<gemmGrid,256,0,stream>>>(T, Wt2, bias2, bat, outp, N, NB);
  k_div<<<(out_size+255)/256,256,0,stream>>>(outp, cg, out_size);
}